// Round 1
// baseline (470.793 us; speedup 1.0000x reference)
//
#include <hip/hip_runtime.h>
#include <math.h>

#define NIMG 8
#define CIN 8
#define Hh 136
#define Ww 200
#define OH 272
#define OW 400
#define NINST 512
#define NPAR 169
#define TROWS 34
#define NTILES 8
#define LROWS 19

__global__ __launch_bounds__(256) void dmh_main(
    const float* __restrict__ feats,
    const float* __restrict__ pars,
    const float* __restrict__ iloc,
    const float* __restrict__ gt,
    const int* __restrict__ iminds,
    const int* __restrict__ lvls,
    float* __restrict__ acc)
{
    __shared__ float slog[LROWS * Ww];
    __shared__ float sred[12];

    const int n    = blockIdx.y;
    const int tile = blockIdx.x;
    const int tid  = threadIdx.x;

    // ---- load per-instance params into registers (wave-uniform -> s_load) ----
    const float* pp = pars + n * NPAR;
    float w0[80], w1[64], w2[8], b0[8], b1[8], b2;
#pragma unroll
    for (int i = 0; i < 80; i++) w0[i] = pp[i];
#pragma unroll
    for (int i = 0; i < 64; i++) w1[i] = pp[80 + i];
#pragma unroll
    for (int i = 0; i < 8; i++)  w2[i] = pp[144 + i];
#pragma unroll
    for (int i = 0; i < 8; i++)  b0[i] = pp[152 + i];
#pragma unroll
    for (int i = 0; i < 8; i++)  b1[i] = pp[160 + i];
    b2 = pp[168];

    const float ix = iloc[2 * n + 0];
    const float iy = iloc[2 * n + 1];
    const int   im = iminds[n];
    const float invsoi = 1.0f / (float)(64 << lvls[n]);

    const float sy = 135.0f / 271.0f;
    const float sx = 199.0f / 399.0f;

    const int oy0 = tile * TROWS;
    const int ly0 = (int)((float)oy0 * sy);
    int lyL = (int)((float)(oy0 + TROWS - 1) * sy) + 1;
    if (lyL > Hh - 1) lyL = Hh - 1;
    const int lycnt = lyL - ly0 + 1;

    // ---- Phase A: low-res logits for this tile's rows -> LDS ----
    const float* fb0 = feats + (size_t)im * (CIN * Hh * Ww);
    const int npix = lycnt * Ww;
    for (int i = tid; i < npix; i += 256) {
        const int yy = i / Ww;
        const int x  = i - yy * Ww;
        const int y  = ly0 + yy;
        const float r0 = (ix - (float)(x * 8 + 4)) * invsoi;
        const float r1 = (iy - (float)(y * 8 + 4)) * invsoi;
        const float* fb = fb0 + y * Ww + x;
        float f[8];
#pragma unroll
        for (int c = 0; c < 8; c++) f[c] = fb[c * (Hh * Ww)];
        float h[8];
#pragma unroll
        for (int o = 0; o < 8; o++) {
            float a = b0[o] + w0[o * 10 + 0] * r0 + w0[o * 10 + 1] * r1;
#pragma unroll
            for (int c = 0; c < 8; c++) a += w0[o * 10 + 2 + c] * f[c];
            h[o] = fmaxf(a, 0.0f);
        }
        float g[8];
#pragma unroll
        for (int o = 0; o < 8; o++) {
            float a = b1[o];
#pragma unroll
            for (int c = 0; c < 8; c++) a += w1[o * 8 + c] * h[c];
            g[o] = fmaxf(a, 0.0f);
        }
        float lg = b2;
#pragma unroll
        for (int c = 0; c < 8; c++) lg += w2[c] * g[c];
        slog[i] = lg;
    }
    __syncthreads();

    // ---- Phase B: bilinear up + sigmoid + dice partial sums ----
    float aI = 0.0f, aS = 0.0f, aT = 0.0f;
    const float* gtn = gt + (size_t)n * (OH * OW) + (size_t)oy0 * OW;
    for (int i = tid; i < TROWS * OW; i += 256) {
        const int ry = i / OW;
        const int ox = i - ry * OW;
        const int oy = oy0 + ry;
        const float ysf = (float)oy * sy;
        const float xsf = (float)ox * sx;
        int y0 = (int)ysf, x0 = (int)xsf;
        const float wy = ysf - (float)y0;
        const float wx = xsf - (float)x0;
        int y1 = (y0 + 1 > Hh - 1) ? (Hh - 1) : (y0 + 1);
        int x1 = (x0 + 1 > Ww - 1) ? (Ww - 1) : (x0 + 1);
        int r0i = y0 - ly0, r1i = y1 - ly0;
        r0i = r0i < 0 ? 0 : (r0i > lycnt - 1 ? lycnt - 1 : r0i);
        r1i = r1i < 0 ? 0 : (r1i > lycnt - 1 ? lycnt - 1 : r1i);
        const float v00 = slog[r0i * Ww + x0];
        const float v01 = slog[r0i * Ww + x1];
        const float v10 = slog[r1i * Ww + x0];
        const float v11 = slog[r1i * Ww + x1];
        const float top = v00 * (1.0f - wx) + v01 * wx;
        const float bot = v10 * (1.0f - wx) + v11 * wx;
        const float v   = top * (1.0f - wy) + bot * wy;
        const float s   = __fdividef(1.0f, 1.0f + __expf(-v));
        const float t   = gtn[i];
        aI += s * t;
        aS += s * s;
        aT += t;
    }

    // ---- block reduction (wave shuffle, then LDS across 4 waves) ----
#pragma unroll
    for (int off = 32; off > 0; off >>= 1) {
        aI += __shfl_down(aI, off, 64);
        aS += __shfl_down(aS, off, 64);
        aT += __shfl_down(aT, off, 64);
    }
    const int wv = tid >> 6;
    if ((tid & 63) == 0) {
        sred[wv * 3 + 0] = aI;
        sred[wv * 3 + 1] = aS;
        sred[wv * 3 + 2] = aT;
    }
    __syncthreads();
    if (tid == 0) {
        const float I = sred[0] + sred[3] + sred[6] + sred[9];
        const float S = sred[1] + sred[4] + sred[7] + sred[10];
        const float T = sred[2] + sred[5] + sred[8] + sred[11];
        atomicAdd(&acc[n * 3 + 0], I);
        atomicAdd(&acc[n * 3 + 1], S);
        atomicAdd(&acc[n * 3 + 2], T);
    }
}

__global__ __launch_bounds__(256) void dmh_fin(const float* __restrict__ acc,
                                               float* __restrict__ out)
{
    const int i = blockIdx.x * 256 + threadIdx.x;
    if (i < NINST) {
        const float I = acc[i * 3 + 0];
        const float S = acc[i * 3 + 1];
        const float T = acc[i * 3 + 2];
        out[i] = 1.0f - 2.0f * I / (S + T + 1e-5f);
    }
}

extern "C" void kernel_launch(void* const* d_in, const int* in_sizes, int n_in,
                              void* d_out, int out_size, void* d_ws, size_t ws_size,
                              hipStream_t stream) {
    const float* feats  = (const float*)d_in[0];
    const float* pars   = (const float*)d_in[1];
    const float* iloc   = (const float*)d_in[2];
    const float* gt     = (const float*)d_in[3];
    const int*   iminds = (const int*)d_in[4];
    const int*   lvls   = (const int*)d_in[5];
    float* acc = (float*)d_ws;

    hipMemsetAsync(acc, 0, NINST * 3 * sizeof(float), stream);
    dim3 grid(NTILES, NINST);
    dmh_main<<<grid, 256, 0, stream>>>(feats, pars, iloc, gt, iminds, lvls, acc);
    dmh_fin<<<(NINST + 255) / 256, 256, 0, stream>>>(acc, (float*)d_out);
}